// Round 1
// baseline (11201.315 us; speedup 1.0000x reference)
//
#include <hip/hip_runtime.h>
#include <cstdint>
#include <cstddef>

#define NN 50000
#define NE 1600000
#define XD 1025

__device__ __forceinline__ float relu_f(float v) { return v > 0.f ? v : 0.f; }

// ---------------- generic tiled f32 GEMM: C = act(A@B + bias) ----------------
// A: (M,K) lda, B: (K,N) ldb row-major, C: (M,N) ldc. N = gridDim.x*64 (must be mult of 64).
// K must be multiple of 16. M guarded.
template <int ACT>
__global__ __launch_bounds__(256) void gemm64(
    const float* __restrict__ A, int lda,
    const float* __restrict__ B, int ldb,
    float* __restrict__ C, int ldc,
    const float* __restrict__ bias,
    int M, int K)
{
    __shared__ float As[64][17];
    __shared__ float Bs[16][64];
    const int tid = threadIdx.x;
    const int tx = tid & 15;
    const int ty = tid >> 4;           // 0..15
    const int brow = blockIdx.y << 6;
    const int bcol = blockIdx.x << 6;

    float acc[4][4] = {};

    for (int k0 = 0; k0 < K; k0 += 16) {
#pragma unroll
        for (int p = 0; p < 4; ++p) {
            int r = ty + (p << 4);
            int gr = brow + r;
            float v = 0.f;
            if (gr < M) v = A[(size_t)gr * lda + (k0 + tx)];
            As[r][tx] = v;
        }
#pragma unroll
        for (int p = 0; p < 4; ++p) {
            int kk = (tid >> 6) + (p << 2);
            Bs[kk][tid & 63] = B[(size_t)(k0 + kk) * ldb + (bcol + (tid & 63))];
        }
        __syncthreads();
#pragma unroll
        for (int kk = 0; kk < 16; ++kk) {
            const float4 b4 = *(const float4*)(&Bs[kk][tx << 2]);
            const float a0 = As[ty][kk];
            const float a1 = As[ty + 16][kk];
            const float a2 = As[ty + 32][kk];
            const float a3 = As[ty + 48][kk];
            acc[0][0] = fmaf(a0, b4.x, acc[0][0]); acc[0][1] = fmaf(a0, b4.y, acc[0][1]);
            acc[0][2] = fmaf(a0, b4.z, acc[0][2]); acc[0][3] = fmaf(a0, b4.w, acc[0][3]);
            acc[1][0] = fmaf(a1, b4.x, acc[1][0]); acc[1][1] = fmaf(a1, b4.y, acc[1][1]);
            acc[1][2] = fmaf(a1, b4.z, acc[1][2]); acc[1][3] = fmaf(a1, b4.w, acc[1][3]);
            acc[2][0] = fmaf(a2, b4.x, acc[2][0]); acc[2][1] = fmaf(a2, b4.y, acc[2][1]);
            acc[2][2] = fmaf(a2, b4.z, acc[2][2]); acc[2][3] = fmaf(a2, b4.w, acc[2][3]);
            acc[3][0] = fmaf(a3, b4.x, acc[3][0]); acc[3][1] = fmaf(a3, b4.y, acc[3][1]);
            acc[3][2] = fmaf(a3, b4.z, acc[3][2]); acc[3][3] = fmaf(a3, b4.w, acc[3][3]);
        }
        __syncthreads();
    }
#pragma unroll
    for (int i = 0; i < 4; ++i) {
        int row = brow + ty + (i << 4);
        if (row >= M) continue;
        int col = bcol + (tx << 2);
        float4 r;
        r.x = acc[i][0]; r.y = acc[i][1]; r.z = acc[i][2]; r.w = acc[i][3];
        if (bias) {
            r.x += bias[col + 0]; r.y += bias[col + 1];
            r.z += bias[col + 2]; r.w += bias[col + 3];
        }
        if (ACT == 1) {
            r.x = relu_f(r.x); r.y = relu_f(r.y); r.z = relu_f(r.z); r.w = relu_f(r.w);
        }
        *(float4*)(&C[(size_t)row * ldc + col]) = r;
    }
}

// ---------------- gw branch: p3[n][c] = relu(gw[n]*w_gw[c] + b_gw[c]) ----------------
__global__ __launch_bounds__(256) void gw_kernel(
    const float* __restrict__ x, const float* __restrict__ w_gw,
    const float* __restrict__ b_gw, float* __restrict__ p3, int nc, int c0)
{
    int idx = blockIdx.x * 256 + threadIdx.x;
    if (idx >= nc * 64) return;
    int n = idx >> 6;
    int c = (idx & 63) << 2;
    float g = x[(size_t)(c0 + n) * XD + 1024];
    float4 w4 = *(const float4*)(w_gw + c);
    float4 b4 = *(const float4*)(b_gw + c);
    float4 r;
    r.x = relu_f(fmaf(g, w4.x, b4.x));
    r.y = relu_f(fmaf(g, w4.y, b4.y));
    r.z = relu_f(fmaf(g, w4.z, b4.z));
    r.w = relu_f(fmaf(g, w4.w, b4.w));
    *(float4*)(p3 + (size_t)n * 256 + c) = r;
}

// ---------------- per-node attention: 1 wave per node ----------------
// qkv rows r = t*NC + n, 768 cols [q|k|v], head h dims h*64..h*64+63. o rows same, 256 cols.
__global__ __launch_bounds__(256) void attn_kernel(
    const float* __restrict__ qkv, float* __restrict__ o, int NC)
{
    __shared__ float sattn[4][64];
    const int w = threadIdx.x >> 6;
    const int lane = threadIdx.x & 63;
    int n = blockIdx.x * 4 + w;
    bool valid = n < NC;
    int nn = valid ? n : 0;

    const int h = lane >> 4, i = (lane >> 2) & 3, j = lane & 3;
    const float* qrow = qkv + (size_t)(i * NC + nn) * 768 + h * 64;
    const float* krow = qkv + (size_t)(j * NC + nn) * 768 + 256 + h * 64;
    float s = 0.f;
#pragma unroll
    for (int d = 0; d < 64; d += 4) {
        float4 qa = *(const float4*)(qrow + d);
        float4 ka = *(const float4*)(krow + d);
        s += qa.x * ka.x + qa.y * ka.y + qa.z * ka.z + qa.w * ka.w;
    }
    s *= 0.125f;  // 1/sqrt(64)
    float m = fmaxf(s, __shfl_xor(s, 1));
    m = fmaxf(m, __shfl_xor(m, 2));
    float e = expf(s - m);
    float sum = e + __shfl_xor(e, 1);
    sum += __shfl_xor(sum, 2);
    float attn = e / sum;
    sattn[w][lane] = attn;
    __syncthreads();

    const int h2 = lane >> 4, db = lane & 15;
    const float* vbase = qkv + 512 + h2 * 64 + (db << 2);
    float4 vj[4];
#pragma unroll
    for (int j2 = 0; j2 < 4; ++j2)
        vj[j2] = *(const float4*)(vbase + (size_t)(j2 * NC + nn) * 768);
#pragma unroll
    for (int i2 = 0; i2 < 4; ++i2) {
        float4 a4 = {0.f, 0.f, 0.f, 0.f};
#pragma unroll
        for (int j2 = 0; j2 < 4; ++j2) {
            float a = sattn[w][h2 * 16 + i2 * 4 + j2];
            a4.x = fmaf(a, vj[j2].x, a4.x);
            a4.y = fmaf(a, vj[j2].y, a4.y);
            a4.z = fmaf(a, vj[j2].z, a4.z);
            a4.w = fmaf(a, vj[j2].w, a4.w);
        }
        if (valid)
            *(float4*)(o + (size_t)(i2 * NC + nn) * 256 + h2 * 64 + (db << 2)) = a4;
    }
}

// ---------------- mean over 4 tokens ----------------
__global__ __launch_bounds__(256) void mean_kernel(
    const float* __restrict__ oo, float* __restrict__ fused, int nc, int c0)
{
    int idx = blockIdx.x * 256 + threadIdx.x;
    if (idx >= nc * 64) return;
    int n = idx >> 6;
    int c = (idx & 63) << 2;
    float4 a = {0.f, 0.f, 0.f, 0.f};
#pragma unroll
    for (int t = 0; t < 4; ++t) {
        float4 v = *(const float4*)(oo + (size_t)(t * nc + n) * 256 + c);
        a.x += v.x; a.y += v.y; a.z += v.z; a.w += v.w;
    }
    a.x *= 0.25f; a.y *= 0.25f; a.z *= 0.25f; a.w *= 0.25f;
    *(float4*)(fused + (size_t)(c0 + n) * 256 + c) = a;
}

// ---------------- transpose: Bt[c][r] = B[r][c], B is (R,C) ----------------
__global__ __launch_bounds__(256) void transpose_kernel(
    const float* __restrict__ B, float* __restrict__ Bt, int R, int C)
{
    int idx = blockIdx.x * 256 + threadIdx.x;
    if (idx >= R * C) return;
    int c = idx / R;
    int r = idx - c * R;
    Bt[idx] = B[(size_t)r * C + c];
}

// ---------------- degree / dinv ----------------
__global__ __launch_bounds__(256) void deg_kernel(
    const int* __restrict__ dst, float* __restrict__ deg, int E)
{
    for (int e = blockIdx.x * 256 + threadIdx.x; e < E; e += gridDim.x * 256)
        atomicAdd(&deg[dst[e]], 1.0f);
}

__global__ __launch_bounds__(256) void dinv_kernel(float* __restrict__ d, int N)
{
    int n = blockIdx.x * 256 + threadIdx.x;
    if (n < N) d[n] = rsqrtf(d[n] + 1.0f);  // +1 self loop
}

// ---------------- GCN: init with self-loop term ----------------
template <int LOGF4>
__global__ __launch_bounds__(256) void gcn_init(
    const float* __restrict__ hw, const float* __restrict__ dinv,
    float* __restrict__ outb, long total4)
{
    long idx = blockIdx.x * 256L + threadIdx.x;
    if (idx >= total4) return;
    int n = (int)(idx >> LOGF4);
    float s = dinv[n] * dinv[n];
    float4 v = *(const float4*)(hw + idx * 4);
    v.x *= s; v.y *= s; v.z *= s; v.w *= s;
    *(float4*)(outb + idx * 4) = v;
}

// ---------------- GCN: edge scatter with atomics ----------------
template <int LOGF4>
__global__ __launch_bounds__(256) void gcn_scatter(
    const int* __restrict__ ei, const float* __restrict__ hw,
    const float* __restrict__ dinv, float* __restrict__ outb, long total)
{
    const int F4 = 1 << LOGF4;
    const int F = F4 << 2;
    for (long idx = blockIdx.x * 256L + threadIdx.x; idx < total; idx += (long)gridDim.x * 256L) {
        int e = (int)(idx >> LOGF4);
        int c = ((int)idx & (F4 - 1)) << 2;
        int src = ei[e];
        int dst = ei[NE + e];
        float nrm = dinv[src] * dinv[dst];
        float4 v = *(const float4*)(hw + (size_t)src * F + c);
        float* ob = outb + (size_t)dst * F + c;
        atomicAdd(ob + 0, nrm * v.x);
        atomicAdd(ob + 1, nrm * v.y);
        atomicAdd(ob + 2, nrm * v.z);
        atomicAdd(ob + 3, nrm * v.w);
    }
}

// ---------------- bias (+relu) ----------------
template <int ACT, int LOGF4>
__global__ __launch_bounds__(256) void bias_act(
    float* __restrict__ h, const float* __restrict__ b, long total4)
{
    long idx = blockIdx.x * 256L + threadIdx.x;
    if (idx >= total4) return;
    int c = ((int)idx & ((1 << LOGF4) - 1)) << 2;
    float4 v = *(float4*)(h + idx * 4);
    float4 b4 = *(const float4*)(b + c);
    v.x += b4.x; v.y += b4.y; v.z += b4.z; v.w += b4.w;
    if (ACT == 1) { v.x = relu_f(v.x); v.y = relu_f(v.y); v.z = relu_f(v.z); v.w = relu_f(v.w); }
    *(float4*)(h + idx * 4) = v;
}

extern "C" void kernel_launch(void* const* d_in, const int* in_sizes, int n_in,
                              void* d_out, int out_size, void* d_ws, size_t ws_size,
                              hipStream_t stream)
{
    const float* x    = (const float*)d_in[0];
    const int*   ei   = (const int*)d_in[1];
    const float* w_go = (const float*)d_in[2];
    const float* b_go = (const float*)d_in[3];
    const float* w_re = (const float*)d_in[4];
    const float* b_re = (const float*)d_in[5];
    const float* w_me = (const float*)d_in[6];
    const float* b_me = (const float*)d_in[7];
    const float* w_gw = (const float*)d_in[8];
    const float* b_gw = (const float*)d_in[9];
    const float* ipw  = (const float*)d_in[10];
    const float* ipb  = (const float*)d_in[11];
    const float* opw  = (const float*)d_in[12];
    const float* opb  = (const float*)d_in[13];
    const float* w1   = (const float*)d_in[14];
    const float* b1   = (const float*)d_in[15];
    const float* w2   = (const float*)d_in[16];
    const float* b2   = (const float*)d_in[17];
    float* out = (float*)d_out;
    float* ws  = (float*)d_ws;

    size_t off = 0;
    auto alloc = [&](size_t nf) { size_t o = off; off += (nf + 63) & ~(size_t)63; return o; };
    const size_t o_dinv  = alloc(NN);
    const size_t o_ipT   = alloc((size_t)256 * 768);
    const size_t o_opT   = alloc((size_t)256 * 256);
    const size_t o_fused = alloc((size_t)NN * 256);
    const size_t o_h1    = alloc((size_t)NN * 256);
    const size_t o_hw    = alloc((size_t)NN * 256);
    (void)o_hw;
    // chunk scratch (p + qkv) overlays h1+hw+tail: those are only live in the GCN phase.
    const size_t o_chunk = o_h1;

    size_t ws_f = ws_size / 4;
    long NC = 256;
    if (ws_f > o_chunk) {
        long cap = (long)((ws_f - o_chunk) / 4096);  // 4*256 + 4*768 floats per node
        if (cap > NC) NC = cap;
    }
    if (NC > NN) NC = NN;

    // deg / dinv  (dst row is ei + NE)
    hipMemsetAsync(ws + o_dinv, 0, NN * sizeof(float), stream);
    deg_kernel<<<1024, 256, 0, stream>>>(ei + NE, ws + o_dinv, NE);
    dinv_kernel<<<(NN + 255) / 256, 256, 0, stream>>>(ws + o_dinv, NN);

    // weight transposes (wq|wk|wv rows -> in_projT (256,768); out_projT (256,256))
    transpose_kernel<<<(768 * 256 + 255) / 256, 256, 0, stream>>>(ipw, ws + o_ipT, 768, 256);
    transpose_kernel<<<(256 * 256 + 255) / 256, 256, 0, stream>>>(opw, ws + o_opT, 256, 256);

    // ---- node-dense phase, chunked over nodes ----
    for (long c0 = 0; c0 < NN; c0 += NC) {
        long nc = (NN - c0 < NC) ? (NN - c0) : NC;
        float* p   = ws + o_chunk;                 // (4, nc, 256) branch-major
        float* qkv = p + (size_t)nc * 1024;        // (4*nc, 768)

        dim3 gP(4, (unsigned)((nc + 63) / 64));
        gemm64<1><<<gP, 256, 0, stream>>>(x + (size_t)c0 * XD,       XD, w_go, 256, p,                    256, b_go, (int)nc, 512);
        gemm64<1><<<gP, 256, 0, stream>>>(x + (size_t)c0 * XD + 512, XD, w_re, 256, p + (size_t)nc * 256, 256, b_re, (int)nc, 256);
        gemm64<1><<<gP, 256, 0, stream>>>(x + (size_t)c0 * XD + 768, XD, w_me, 256, p + (size_t)nc * 512, 256, b_me, (int)nc, 256);
        gw_kernel<<<(unsigned)((nc * 64 + 255) / 256), 256, 0, stream>>>(x, w_gw, b_gw, p + (size_t)nc * 768, (int)nc, (int)c0);

        dim3 gQ(12, (unsigned)((4 * nc + 63) / 64));
        gemm64<0><<<gQ, 256, 0, stream>>>(p, 256, ws + o_ipT, 768, qkv, 768, ipb, (int)(4 * nc), 256);

        attn_kernel<<<(unsigned)((nc + 3) / 4), 256, 0, stream>>>(qkv, p, (int)nc);  // o overlays p

        dim3 gO(4, (unsigned)((4 * nc + 63) / 64));
        gemm64<0><<<gO, 256, 0, stream>>>(p, 256, ws + o_opT, 256, qkv, 256, opb, (int)(4 * nc), 256);  // oo overlays qkv

        mean_kernel<<<(unsigned)((nc * 64 + 255) / 256), 256, 0, stream>>>(qkv, ws + o_fused, (int)nc, (int)c0);
    }

    // ---- GCN layer 1: h1 = relu(norm-scatter(fused @ w1) + b1) ----
    dim3 gH(4, (NN + 63) / 64);
    gemm64<0><<<gH, 256, 0, stream>>>(ws + o_fused, 256, w1, 256, ws + o_hw, 256, nullptr, NN, 256);
    gcn_init<6><<<((long)NN * 64 + 255) / 256, 256, 0, stream>>>(ws + o_hw, ws + o_dinv, ws + o_h1, (long)NN * 64);
    gcn_scatter<6><<<8192, 256, 0, stream>>>(ei, ws + o_hw, ws + o_dinv, ws + o_h1, (long)NE * 64);
    bias_act<1, 6><<<((long)NN * 64 + 255) / 256, 256, 0, stream>>>(ws + o_h1, b1, (long)NN * 64);

    // ---- GCN layer 2: out = norm-scatter(h1 @ w2) + b2 ----
    dim3 gH2(2, (NN + 63) / 64);
    gemm64<0><<<gH2, 256, 0, stream>>>(ws + o_h1, 256, w2, 128, ws + o_hw, 128, nullptr, NN, 256);
    gcn_init<5><<<((long)NN * 32 + 255) / 256, 256, 0, stream>>>(ws + o_hw, ws + o_dinv, out, (long)NN * 32);
    gcn_scatter<5><<<8192, 256, 0, stream>>>(ei, ws + o_hw, ws + o_dinv, out, (long)NE * 32);
    bias_act<0, 5><<<((long)NN * 32 + 255) / 256, 256, 0, stream>>>(out, b2, (long)NN * 32);
}

// Round 2
// 3356.638 us; speedup vs baseline: 3.3371x; 3.3371x over previous
//
#include <hip/hip_runtime.h>
#include <cstdint>
#include <cstddef>

#define NN 50000
#define NE 1600000
#define XD 1025

__device__ __forceinline__ float relu_f(float v) { return v > 0.f ? v : 0.f; }

// ---------------- generic tiled f32 GEMM: C = act(A@B + bias) ----------------
template <int ACT>
__global__ __launch_bounds__(256) void gemm64(
    const float* __restrict__ A, int lda,
    const float* __restrict__ B, int ldb,
    float* __restrict__ C, int ldc,
    const float* __restrict__ bias,
    int M, int K)
{
    __shared__ float As[64][17];
    __shared__ float Bs[16][64];
    const int tid = threadIdx.x;
    const int tx = tid & 15;
    const int ty = tid >> 4;           // 0..15
    const int brow = blockIdx.y << 6;
    const int bcol = blockIdx.x << 6;

    float acc[4][4] = {};

    for (int k0 = 0; k0 < K; k0 += 16) {
#pragma unroll
        for (int p = 0; p < 4; ++p) {
            int r = ty + (p << 4);
            int gr = brow + r;
            float v = 0.f;
            if (gr < M) v = A[(size_t)gr * lda + (k0 + tx)];
            As[r][tx] = v;
        }
#pragma unroll
        for (int p = 0; p < 4; ++p) {
            int kk = (tid >> 6) + (p << 2);
            Bs[kk][tid & 63] = B[(size_t)(k0 + kk) * ldb + (bcol + (tid & 63))];
        }
        __syncthreads();
#pragma unroll
        for (int kk = 0; kk < 16; ++kk) {
            const float4 b4 = *(const float4*)(&Bs[kk][tx << 2]);
            const float a0 = As[ty][kk];
            const float a1 = As[ty + 16][kk];
            const float a2 = As[ty + 32][kk];
            const float a3 = As[ty + 48][kk];
            acc[0][0] = fmaf(a0, b4.x, acc[0][0]); acc[0][1] = fmaf(a0, b4.y, acc[0][1]);
            acc[0][2] = fmaf(a0, b4.z, acc[0][2]); acc[0][3] = fmaf(a0, b4.w, acc[0][3]);
            acc[1][0] = fmaf(a1, b4.x, acc[1][0]); acc[1][1] = fmaf(a1, b4.y, acc[1][1]);
            acc[1][2] = fmaf(a1, b4.z, acc[1][2]); acc[1][3] = fmaf(a1, b4.w, acc[1][3]);
            acc[2][0] = fmaf(a2, b4.x, acc[2][0]); acc[2][1] = fmaf(a2, b4.y, acc[2][1]);
            acc[2][2] = fmaf(a2, b4.z, acc[2][2]); acc[2][3] = fmaf(a2, b4.w, acc[2][3]);
            acc[3][0] = fmaf(a3, b4.x, acc[3][0]); acc[3][1] = fmaf(a3, b4.y, acc[3][1]);
            acc[3][2] = fmaf(a3, b4.z, acc[3][2]); acc[3][3] = fmaf(a3, b4.w, acc[3][3]);
        }
        __syncthreads();
    }
#pragma unroll
    for (int i = 0; i < 4; ++i) {
        int row = brow + ty + (i << 4);
        if (row >= M) continue;
        int col = bcol + (tx << 2);
        float4 r;
        r.x = acc[i][0]; r.y = acc[i][1]; r.z = acc[i][2]; r.w = acc[i][3];
        if (bias) {
            r.x += bias[col + 0]; r.y += bias[col + 1];
            r.z += bias[col + 2]; r.w += bias[col + 3];
        }
        if (ACT == 1) {
            r.x = relu_f(r.x); r.y = relu_f(r.y); r.z = relu_f(r.z); r.w = relu_f(r.w);
        }
        *(float4*)(&C[(size_t)row * ldc + col]) = r;
    }
}

// ---------------- gw branch ----------------
__global__ __launch_bounds__(256) void gw_kernel(
    const float* __restrict__ x, const float* __restrict__ w_gw,
    const float* __restrict__ b_gw, float* __restrict__ p3, int nc, int c0)
{
    int idx = blockIdx.x * 256 + threadIdx.x;
    if (idx >= nc * 64) return;
    int n = idx >> 6;
    int c = (idx & 63) << 2;
    float g = x[(size_t)(c0 + n) * XD + 1024];
    float4 w4 = *(const float4*)(w_gw + c);
    float4 b4 = *(const float4*)(b_gw + c);
    float4 r;
    r.x = relu_f(fmaf(g, w4.x, b4.x));
    r.y = relu_f(fmaf(g, w4.y, b4.y));
    r.z = relu_f(fmaf(g, w4.z, b4.z));
    r.w = relu_f(fmaf(g, w4.w, b4.w));
    *(float4*)(p3 + (size_t)n * 256 + c) = r;
}

// ---------------- per-node attention: 1 wave per node ----------------
__global__ __launch_bounds__(256) void attn_kernel(
    const float* __restrict__ qkv, float* __restrict__ o, int NC)
{
    __shared__ float sattn[4][64];
    const int w = threadIdx.x >> 6;
    const int lane = threadIdx.x & 63;
    int n = blockIdx.x * 4 + w;
    bool valid = n < NC;
    int nn = valid ? n : 0;

    const int h = lane >> 4, i = (lane >> 2) & 3, j = lane & 3;
    const float* qrow = qkv + (size_t)(i * NC + nn) * 768 + h * 64;
    const float* krow = qkv + (size_t)(j * NC + nn) * 768 + 256 + h * 64;
    float s = 0.f;
#pragma unroll
    for (int d = 0; d < 64; d += 4) {
        float4 qa = *(const float4*)(qrow + d);
        float4 ka = *(const float4*)(krow + d);
        s += qa.x * ka.x + qa.y * ka.y + qa.z * ka.z + qa.w * ka.w;
    }
    s *= 0.125f;  // 1/sqrt(64)
    float m = fmaxf(s, __shfl_xor(s, 1));
    m = fmaxf(m, __shfl_xor(m, 2));
    float e = expf(s - m);
    float sum = e + __shfl_xor(e, 1);
    sum += __shfl_xor(sum, 2);
    float attn = e / sum;
    sattn[w][lane] = attn;
    __syncthreads();

    const int h2 = lane >> 4, db = lane & 15;
    const float* vbase = qkv + 512 + h2 * 64 + (db << 2);
    float4 vj[4];
#pragma unroll
    for (int j2 = 0; j2 < 4; ++j2)
        vj[j2] = *(const float4*)(vbase + (size_t)(j2 * NC + nn) * 768);
#pragma unroll
    for (int i2 = 0; i2 < 4; ++i2) {
        float4 a4 = {0.f, 0.f, 0.f, 0.f};
#pragma unroll
        for (int j2 = 0; j2 < 4; ++j2) {
            float a = sattn[w][h2 * 16 + i2 * 4 + j2];
            a4.x = fmaf(a, vj[j2].x, a4.x);
            a4.y = fmaf(a, vj[j2].y, a4.y);
            a4.z = fmaf(a, vj[j2].z, a4.z);
            a4.w = fmaf(a, vj[j2].w, a4.w);
        }
        if (valid)
            *(float4*)(o + (size_t)(i2 * NC + nn) * 256 + h2 * 64 + (db << 2)) = a4;
    }
}

// ---------------- mean over 4 tokens ----------------
__global__ __launch_bounds__(256) void mean_kernel(
    const float* __restrict__ oo, float* __restrict__ fused, int nc, int c0)
{
    int idx = blockIdx.x * 256 + threadIdx.x;
    if (idx >= nc * 64) return;
    int n = idx >> 6;
    int c = (idx & 63) << 2;
    float4 a = {0.f, 0.f, 0.f, 0.f};
#pragma unroll
    for (int t = 0; t < 4; ++t) {
        float4 v = *(const float4*)(oo + (size_t)(t * nc + n) * 256 + c);
        a.x += v.x; a.y += v.y; a.z += v.z; a.w += v.w;
    }
    a.x *= 0.25f; a.y *= 0.25f; a.z *= 0.25f; a.w *= 0.25f;
    *(float4*)(fused + (size_t)(c0 + n) * 256 + c) = a;
}

// ---------------- transpose ----------------
__global__ __launch_bounds__(256) void transpose_kernel(
    const float* __restrict__ B, float* __restrict__ Bt, int R, int C)
{
    int idx = blockIdx.x * 256 + threadIdx.x;
    if (idx >= R * C) return;
    int c = idx / R;
    int r = idx - c * R;
    Bt[idx] = B[(size_t)r * C + c];
}

// ---------------- CSR build: degree histogram (int) ----------------
__global__ __launch_bounds__(256) void deg_int_kernel(
    const int* __restrict__ dst, int* __restrict__ deg, int E)
{
    for (int e = blockIdx.x * 256 + threadIdx.x; e < E; e += gridDim.x * 256)
        atomicAdd(&deg[dst[e]], 1);
}

__global__ __launch_bounds__(256) void dinv_kernel(
    const int* __restrict__ deg, float* __restrict__ dinv, int N)
{
    int n = blockIdx.x * 256 + threadIdx.x;
    if (n < N) dinv[n] = rsqrtf((float)deg[n] + 1.0f);  // +1 self loop
}

// ---------------- single-block hierarchical exclusive scan ----------------
__global__ __launch_bounds__(1024) void scan_kernel(
    const int* __restrict__ deg, int* __restrict__ offs, int N)
{
    __shared__ int wsum[16];
    __shared__ int s_carry;
    const int tid = threadIdx.x;
    const int lane = tid & 63;
    const int w = tid >> 6;
    if (tid == 0) s_carry = 0;
    __syncthreads();
    for (int base = 0; base < N; base += 1024) {
        int i = base + tid;
        int v = (i < N) ? deg[i] : 0;
        int x = v;
#pragma unroll
        for (int d = 1; d < 64; d <<= 1) {
            int t = __shfl_up(x, d);
            if (lane >= d) x += t;
        }
        if (lane == 63) wsum[w] = x;
        __syncthreads();
        if (w == 0 && lane < 16) {
            int y = wsum[lane];
#pragma unroll
            for (int d = 1; d < 16; d <<= 1) {
                int t = __shfl_up(y, d);
                if (lane >= d) y += t;
            }
            wsum[lane] = y;   // inclusive per-wave prefix
        }
        __syncthreads();
        int waveoff = (w == 0) ? 0 : wsum[w - 1];
        if (i < N) offs[i] = s_carry + waveoff + x - v;
        __syncthreads();
        if (tid == 0) s_carry += wsum[15];
        __syncthreads();
    }
    if (tid == 0) offs[N] = s_carry;
}

// ---------------- CSR fill ----------------
__global__ __launch_bounds__(256) void csr_fill(
    const int* __restrict__ ei, const int* __restrict__ offs,
    int* __restrict__ cursor, int* __restrict__ csr_src,
    float* __restrict__ csr_nrm, const float* __restrict__ dinv, int E)
{
    for (int e = blockIdx.x * 256 + threadIdx.x; e < E; e += gridDim.x * 256) {
        int s = ei[e];
        int d = ei[NE + e];
        int pos = offs[d] + atomicAdd(&cursor[d], 1);
        csr_src[pos] = s;
        csr_nrm[pos] = dinv[s] * dinv[d];
    }
}

// ---------------- GCN gather: one wave per dst node, fused self+bias+act ----------------
// F = feature count (256 or 128), VEC = F/64 floats per lane
template <int F, int ACT>
__global__ __launch_bounds__(256) void gcn_gather(
    const int* __restrict__ offs, const int* __restrict__ csr_src,
    const float* __restrict__ csr_nrm, const float* __restrict__ hw,
    const float* __restrict__ dinv, const float* __restrict__ bias,
    float* __restrict__ outb, int N)
{
    constexpr int VEC = F / 64;
    const int wid = blockIdx.x * 4 + (threadIdx.x >> 6);
    const int lane = threadIdx.x & 63;
    if (wid >= N) return;
    const int col = lane * VEC;

    float acc[VEC];
    float self = dinv[wid] * dinv[wid];
    const float* srow = hw + (size_t)wid * F + col;
#pragma unroll
    for (int j = 0; j < VEC; ++j) acc[j] = self * srow[j];

    const int beg = offs[wid];
    const int end = offs[wid + 1];
    for (int e = beg; e < end; ++e) {
        int src = csr_src[e];
        float nrm = csr_nrm[e];
        const float* row = hw + (size_t)src * F + col;
        if (VEC == 4) {
            float4 v = *(const float4*)row;
            acc[0] = fmaf(nrm, v.x, acc[0]);
            acc[1] = fmaf(nrm, v.y, acc[1]);
            acc[2] = fmaf(nrm, v.z, acc[2]);
            acc[3] = fmaf(nrm, v.w, acc[3]);
        } else {
            float2 v = *(const float2*)row;
            acc[0] = fmaf(nrm, v.x, acc[0]);
            acc[1] = fmaf(nrm, v.y, acc[1]);
        }
    }
#pragma unroll
    for (int j = 0; j < VEC; ++j) {
        float r = acc[j] + bias[col + j];
        if (ACT == 1) r = relu_f(r);
        outb[(size_t)wid * F + col + j] = r;
    }
}

extern "C" void kernel_launch(void* const* d_in, const int* in_sizes, int n_in,
                              void* d_out, int out_size, void* d_ws, size_t ws_size,
                              hipStream_t stream)
{
    const float* x    = (const float*)d_in[0];
    const int*   ei   = (const int*)d_in[1];
    const float* w_go = (const float*)d_in[2];
    const float* b_go = (const float*)d_in[3];
    const float* w_re = (const float*)d_in[4];
    const float* b_re = (const float*)d_in[5];
    const float* w_me = (const float*)d_in[6];
    const float* b_me = (const float*)d_in[7];
    const float* w_gw = (const float*)d_in[8];
    const float* b_gw = (const float*)d_in[9];
    const float* ipw  = (const float*)d_in[10];
    const float* ipb  = (const float*)d_in[11];
    const float* opw  = (const float*)d_in[12];
    const float* opb  = (const float*)d_in[13];
    const float* w1   = (const float*)d_in[14];
    const float* b1   = (const float*)d_in[15];
    const float* w2   = (const float*)d_in[16];
    const float* b2   = (const float*)d_in[17];
    float* out = (float*)d_out;
    float* ws  = (float*)d_ws;

    size_t off = 0;
    auto alloc = [&](size_t nf) { size_t o = off; off += (nf + 63) & ~(size_t)63; return o; };
    const size_t o_dinv  = alloc(NN);
    const size_t o_ipT   = alloc((size_t)256 * 768);
    const size_t o_opT   = alloc((size_t)256 * 256);
    const size_t o_deg   = alloc(NN);            // int
    const size_t o_offs  = alloc(NN + 1);        // int
    const size_t o_cur   = alloc(NN);            // int
    const size_t o_csrs  = alloc(NE);            // int
    const size_t o_csrn  = alloc(NE);            // float
    const size_t o_fused = alloc((size_t)NN * 256);  // doubles as h1 (dead fused by then)
    const size_t o_hw    = off;                  // hw region; also chunk scratch base

    int* i_deg  = (int*)(ws + o_deg);
    int* i_offs = (int*)(ws + o_offs);
    int* i_cur  = (int*)(ws + o_cur);
    int* i_csrs = (int*)(ws + o_csrs);

    // chunk capacity: node phase needs nc*4096 floats from o_hw
    size_t ws_f = ws_size / 4;
    long NC = 256;
    if (ws_f > o_hw + 4096) {
        long cap = (long)((ws_f - o_hw) / 4096);
        if (cap > NC) NC = cap;
    }
    if (NC > NN) NC = NN;

    // ---- CSR build ----
    hipMemsetAsync(i_deg, 0, NN * sizeof(int), stream);
    hipMemsetAsync(i_cur, 0, NN * sizeof(int), stream);
    deg_int_kernel<<<1024, 256, 0, stream>>>(ei + NE, i_deg, NE);
    dinv_kernel<<<(NN + 255) / 256, 256, 0, stream>>>(i_deg, ws + o_dinv, NN);
    scan_kernel<<<1, 1024, 0, stream>>>(i_deg, i_offs, NN);
    csr_fill<<<1024, 256, 0, stream>>>(ei, i_offs, i_cur, i_csrs, ws + o_csrn, ws + o_dinv, NE);

    // ---- weight transposes ----
    transpose_kernel<<<(768 * 256 + 255) / 256, 256, 0, stream>>>(ipw, ws + o_ipT, 768, 256);
    transpose_kernel<<<(256 * 256 + 255) / 256, 256, 0, stream>>>(opw, ws + o_opT, 256, 256);

    // ---- node-dense phase, chunked over nodes ----
    for (long c0 = 0; c0 < NN; c0 += NC) {
        long nc = (NN - c0 < NC) ? (NN - c0) : NC;
        float* p   = ws + o_hw;                    // (4, nc, 256) branch-major
        float* qkv = p + (size_t)nc * 1024;        // (4*nc, 768)

        dim3 gP(4, (unsigned)((nc + 63) / 64));
        gemm64<1><<<gP, 256, 0, stream>>>(x + (size_t)c0 * XD,       XD, w_go, 256, p,                    256, b_go, (int)nc, 512);
        gemm64<1><<<gP, 256, 0, stream>>>(x + (size_t)c0 * XD + 512, XD, w_re, 256, p + (size_t)nc * 256, 256, b_re, (int)nc, 256);
        gemm64<1><<<gP, 256, 0, stream>>>(x + (size_t)c0 * XD + 768, XD, w_me, 256, p + (size_t)nc * 512, 256, b_me, (int)nc, 256);
        gw_kernel<<<(unsigned)((nc * 64 + 255) / 256), 256, 0, stream>>>(x, w_gw, b_gw, p + (size_t)nc * 768, (int)nc, (int)c0);

        dim3 gQ(12, (unsigned)((4 * nc + 63) / 64));
        gemm64<0><<<gQ, 256, 0, stream>>>(p, 256, ws + o_ipT, 768, qkv, 768, ipb, (int)(4 * nc), 256);

        attn_kernel<<<(unsigned)((nc + 3) / 4), 256, 0, stream>>>(qkv, p, (int)nc);  // o overlays p

        dim3 gO(4, (unsigned)((4 * nc + 63) / 64));
        gemm64<0><<<gO, 256, 0, stream>>>(p, 256, ws + o_opT, 256, qkv, 256, opb, (int)(4 * nc), 256);  // oo overlays qkv

        mean_kernel<<<(unsigned)((nc * 64 + 255) / 256), 256, 0, stream>>>(qkv, ws + o_fused, (int)nc, (int)c0);
    }

    // ---- GCN layer 1: h1 = relu(gather(fused @ w1) + b1), h1 overlays fused ----
    dim3 gH(4, (NN + 63) / 64);
    gemm64<0><<<gH, 256, 0, stream>>>(ws + o_fused, 256, w1, 256, ws + o_hw, 256, nullptr, NN, 256);
    gcn_gather<256, 1><<<(NN + 3) / 4, 256, 0, stream>>>(
        i_offs, i_csrs, ws + o_csrn, ws + o_hw, ws + o_dinv, b1, ws + o_fused, NN);

    // ---- GCN layer 2: out = gather(h1 @ w2) + b2 ----
    dim3 gH2(2, (NN + 63) / 64);
    gemm64<0><<<gH2, 256, 0, stream>>>(ws + o_fused, 256, w2, 128, ws + o_hw, 128, nullptr, NN, 256);
    gcn_gather<128, 0><<<(NN + 3) / 4, 256, 0, stream>>>(
        i_offs, i_csrs, ws + o_csrn, ws + o_hw, ws + o_dinv, b2, out, NN);
}

// Round 3
// 1104.234 us; speedup vs baseline: 10.1440x; 3.0398x over previous
//
#include <hip/hip_runtime.h>
#include <cstdint>
#include <cstddef>

#define NN 50000
#define NE 1600000
#define XD 1025

typedef unsigned short ushortt;
typedef __attribute__((ext_vector_type(8))) short short8;
typedef __attribute__((ext_vector_type(4))) float f32x4;

__device__ __forceinline__ float relu_f(float v) { return v > 0.f ? v : 0.f; }
__device__ __forceinline__ float b2f(ushortt u) { return __uint_as_float(((unsigned)u) << 16); }
__device__ __forceinline__ float blo(unsigned u) { return __uint_as_float(u << 16); }
__device__ __forceinline__ float bhi(unsigned u) { return __uint_as_float(u & 0xffff0000u); }
__device__ __forceinline__ ushortt bf16rn(float f) {
    unsigned u = __float_as_uint(f);
    return (ushortt)((u + 0x7fffu + ((u >> 16) & 1u)) >> 16);
}
__device__ __forceinline__ void load_lds16(const void* g, void* l) {
    __builtin_amdgcn_global_load_lds(
        (const __attribute__((address_space(1))) void*)g,
        (__attribute__((address_space(3))) void*)l, 16, 0, 0);
}

// ================= bf16 MFMA GEMM =================
// A: (M,K) bf16 row-major, lda. Bt: (N,K) bf16 row-major (stride K). bias f32 or null.
// OUTMODE 1: C bf16 (M,N) ldc, ACT optional relu.
// OUTMODE 2: mean over groups of 4 rows -> C bf16 (M/4, N) ldc (bias added after mean).
// Grid: (N/128, ceil(M/128)), 256 threads.
template <int ACT, int OUTMODE>
__global__ __launch_bounds__(256) void gemm_mfma(
    const ushortt* __restrict__ A, int lda,
    const ushortt* __restrict__ Bt,
    void* __restrict__ C, int ldc,
    const float* __restrict__ bias,
    int M, int K)
{
    __shared__ ushortt As[128 * 32];   // 64B rows, 16B slots xor-swizzled by row&3
    __shared__ ushortt Bs[128 * 32];
    const int tid = threadIdx.x;
    const int w = tid >> 6, l = tid & 63;
    const int wr = w >> 1, wc = w & 1;
    const int brow = blockIdx.y << 7;
    const int bcol = blockIdx.x << 7;

    f32x4 acc[4][4] = {};

    const int rA0 = wr * 64 + (l & 15);
    const int rB0 = wc * 64 + (l & 15);
    const int kslot = l >> 4;

    for (int k0 = 0; k0 < K; k0 += 32) {
        // ---- stage A,B tiles: per wave 2 calls each, 16 rows per call ----
#pragma unroll
        for (int c = 0; c < 2; ++c) {
            int rl = c * 64 + w * 16 + (l >> 2);
            int csel = (l & 3) ^ (rl & 3);
            int gr = brow + rl; if (gr >= M) gr = M - 1;
            load_lds16(A + (size_t)gr * lda + k0 + csel * 8, &As[(c * 64 + w * 16) * 32]);
        }
#pragma unroll
        for (int c = 0; c < 2; ++c) {
            int rl = c * 64 + w * 16 + (l >> 2);
            int csel = (l & 3) ^ (rl & 3);
            load_lds16(Bt + (size_t)(bcol + rl) * K + k0 + csel * 8, &Bs[(c * 64 + w * 16) * 32]);
        }
        __syncthreads();

        short8 af[4], bf[4];
#pragma unroll
        for (int mi = 0; mi < 4; ++mi) {
            int row = rA0 + mi * 16;
            af[mi] = *(const short8*)&As[row * 32 + ((kslot ^ (row & 3)) << 3)];
        }
#pragma unroll
        for (int ni = 0; ni < 4; ++ni) {
            int row = rB0 + ni * 16;
            bf[ni] = *(const short8*)&Bs[row * 32 + ((kslot ^ (row & 3)) << 3)];
        }
#pragma unroll
        for (int mi = 0; mi < 4; ++mi)
#pragma unroll
            for (int ni = 0; ni < 4; ++ni)
                acc[mi][ni] = __builtin_amdgcn_mfma_f32_16x16x32_bf16(af[mi], bf[ni], acc[mi][ni], 0, 0, 0);
        __syncthreads();
    }

    // ---- epilogue: D col = lane&15, row = (lane>>4)*4 + reg ----
    const int cb = bcol + wc * 64 + (l & 15);
    if (OUTMODE == 1) {
        ushortt* C16 = (ushortt*)C;
        const int rb = brow + wr * 64 + ((l >> 4) << 2);
#pragma unroll
        for (int mi = 0; mi < 4; ++mi) {
#pragma unroll
            for (int ni = 0; ni < 4; ++ni) {
                int col = cb + ni * 16;
                float bv = bias ? bias[col] : 0.f;
#pragma unroll
                for (int r = 0; r < 4; ++r) {
                    int row = rb + mi * 16 + r;
                    if (row < M) {
                        float v = acc[mi][ni][r] + bv;
                        if (ACT == 1) v = relu_f(v);
                        C16[(size_t)row * ldc + col] = bf16rn(v);
                    }
                }
            }
        }
    } else {  // OUTMODE == 2: mean over 4 consecutive rows (tokens), bf16 out
        ushortt* C16 = (ushortt*)C;
        const int nodes = M >> 2;
#pragma unroll
        for (int mi = 0; mi < 4; ++mi) {
            int node = ((brow + wr * 64 + mi * 16) >> 2) + (l >> 4);
            if (node >= nodes) continue;
#pragma unroll
            for (int ni = 0; ni < 4; ++ni) {
                int col = cb + ni * 16;
                float v = 0.25f * (acc[mi][ni][0] + acc[mi][ni][1] + acc[mi][ni][2] + acc[mi][ni][3]);
                v += bias ? bias[col] : 0.f;
                C16[(size_t)node * ldc + col] = bf16rn(v);
            }
        }
    }
}

// ================= conversions =================
// x (NN,1025) f32 -> ago (NN,512), are (NN,256), ame (NN,256) bf16
__global__ __launch_bounds__(256) void conv_x(
    const float* __restrict__ x, ushortt* __restrict__ ago,
    ushortt* __restrict__ are, ushortt* __restrict__ ame)
{
    long idx = blockIdx.x * 256L + threadIdx.x;
    if (idx >= (long)NN * 128) return;
    int n = (int)(idx >> 7);
    int c8 = ((int)idx & 127) << 3;
    const float* src = x + (size_t)n * XD + c8;
    ushortt* dst;
    if (c8 < 512) dst = ago + (size_t)n * 512 + c8;
    else if (c8 < 768) dst = are + (size_t)n * 256 + (c8 - 512);
    else dst = ame + (size_t)n * 256 + (c8 - 768);
    ushort4 o1, o2;
    o1.x = bf16rn(src[0]); o1.y = bf16rn(src[1]); o1.z = bf16rn(src[2]); o1.w = bf16rn(src[3]);
    o2.x = bf16rn(src[4]); o2.y = bf16rn(src[5]); o2.z = bf16rn(src[6]); o2.w = bf16rn(src[7]);
    *(ushort4*)dst = o1;
    *(ushort4*)(dst + 4) = o2;
}

// in (R,C) f32 -> out (C,R) bf16
__global__ __launch_bounds__(256) void convT(
    const float* __restrict__ in, ushortt* __restrict__ out, int R, int C)
{
    int idx = blockIdx.x * 256 + threadIdx.x;
    if (idx >= R * C) return;
    int c = idx / R, r = idx - c * R;
    out[idx] = bf16rn(in[(size_t)r * C + c]);
}

__global__ __launch_bounds__(256) void convF(
    const float* __restrict__ in, ushortt* __restrict__ out, int n)
{
    int idx = blockIdx.x * 256 + threadIdx.x;
    if (idx < n) out[idx] = bf16rn(in[idx]);
}

// ================= gw branch: p row n*4+3 ================
__global__ __launch_bounds__(256) void gw_kernel(
    const float* __restrict__ x, const float* __restrict__ w_gw,
    const float* __restrict__ b_gw, ushortt* __restrict__ p)
{
    long idx = blockIdx.x * 256L + threadIdx.x;
    if (idx >= (long)NN * 64) return;
    int n = (int)(idx >> 6);
    int c = ((int)idx & 63) << 2;
    float g = x[(size_t)n * XD + 1024];
    float4 w4 = *(const float4*)(w_gw + c);
    float4 b4 = *(const float4*)(b_gw + c);
    ushort4 r;
    r.x = bf16rn(relu_f(fmaf(g, w4.x, b4.x)));
    r.y = bf16rn(relu_f(fmaf(g, w4.y, b4.y)));
    r.z = bf16rn(relu_f(fmaf(g, w4.z, b4.z)));
    r.w = bf16rn(relu_f(fmaf(g, w4.w, b4.w)));
    *(ushort4*)(p + (size_t)n * 1024 + 768 + c) = r;
}

// ================= per-node attention (bf16 qkv rows n*4+t) ================
__global__ __launch_bounds__(256) void attn_kernel(
    const ushortt* __restrict__ qkv, ushortt* __restrict__ o, int N)
{
    __shared__ float sattn[4][64];
    const int w = threadIdx.x >> 6;
    const int lane = threadIdx.x & 63;
    int n = blockIdx.x * 4 + w;
    bool valid = n < N;
    int nn = valid ? n : 0;

    const int h = lane >> 4, i = (lane >> 2) & 3, j = lane & 3;
    const ushortt* qrow = qkv + (size_t)(nn * 4 + i) * 768 + h * 64;
    const ushortt* krow = qkv + (size_t)(nn * 4 + j) * 768 + 256 + h * 64;
    float s = 0.f;
#pragma unroll
    for (int d = 0; d < 64; d += 8) {
        uint4 qa = *(const uint4*)(qrow + d);
        uint4 ka = *(const uint4*)(krow + d);
        s += blo(qa.x) * blo(ka.x) + bhi(qa.x) * bhi(ka.x);
        s += blo(qa.y) * blo(ka.y) + bhi(qa.y) * bhi(ka.y);
        s += blo(qa.z) * blo(ka.z) + bhi(qa.z) * bhi(ka.z);
        s += blo(qa.w) * blo(ka.w) + bhi(qa.w) * bhi(ka.w);
    }
    s *= 0.125f;  // 1/sqrt(64)
    float m = fmaxf(s, __shfl_xor(s, 1));
    m = fmaxf(m, __shfl_xor(m, 2));
    float e = expf(s - m);
    float sum = e + __shfl_xor(e, 1);
    sum += __shfl_xor(sum, 2);
    sattn[w][lane] = e / sum;
    __syncthreads();

    const int h2 = lane >> 4, db = lane & 15;
    const ushortt* vbase = qkv + 512 + h2 * 64 + (db << 2);
    float4 vj[4];
#pragma unroll
    for (int j2 = 0; j2 < 4; ++j2) {
        ushort4 vr = *(const ushort4*)(vbase + (size_t)(nn * 4 + j2) * 768);
        vj[j2].x = b2f(vr.x); vj[j2].y = b2f(vr.y); vj[j2].z = b2f(vr.z); vj[j2].w = b2f(vr.w);
    }
#pragma unroll
    for (int i2 = 0; i2 < 4; ++i2) {
        float4 a4 = {0.f, 0.f, 0.f, 0.f};
#pragma unroll
        for (int j2 = 0; j2 < 4; ++j2) {
            float a = sattn[w][h2 * 16 + i2 * 4 + j2];
            a4.x = fmaf(a, vj[j2].x, a4.x);
            a4.y = fmaf(a, vj[j2].y, a4.y);
            a4.z = fmaf(a, vj[j2].z, a4.z);
            a4.w = fmaf(a, vj[j2].w, a4.w);
        }
        if (valid) {
            ushort4 r;
            r.x = bf16rn(a4.x); r.y = bf16rn(a4.y); r.z = bf16rn(a4.z); r.w = bf16rn(a4.w);
            *(ushort4*)(o + (size_t)(nn * 4 + i2) * 256 + h2 * 64 + (db << 2)) = r;
        }
    }
}

// ================= CSR build ================
__global__ __launch_bounds__(256) void deg_int_kernel(
    const int* __restrict__ dst, int* __restrict__ deg, int E)
{
    for (int e = blockIdx.x * 256 + threadIdx.x; e < E; e += gridDim.x * 256)
        atomicAdd(&deg[dst[e]], 1);
}

__global__ __launch_bounds__(256) void dinv_kernel(
    const int* __restrict__ deg, float* __restrict__ dinv, int N)
{
    int n = blockIdx.x * 256 + threadIdx.x;
    if (n < N) dinv[n] = rsqrtf((float)deg[n] + 1.0f);
}

__global__ __launch_bounds__(1024) void scan_kernel(
    const int* __restrict__ deg, int* __restrict__ offs, int N)
{
    __shared__ int wsum[16];
    __shared__ int s_carry;
    const int tid = threadIdx.x;
    const int lane = tid & 63;
    const int w = tid >> 6;
    if (tid == 0) s_carry = 0;
    __syncthreads();
    for (int base = 0; base < N; base += 1024) {
        int i = base + tid;
        int v = (i < N) ? deg[i] : 0;
        int x = v;
#pragma unroll
        for (int d = 1; d < 64; d <<= 1) {
            int t = __shfl_up(x, d);
            if (lane >= d) x += t;
        }
        if (lane == 63) wsum[w] = x;
        __syncthreads();
        if (w == 0 && lane < 16) {
            int y = wsum[lane];
#pragma unroll
            for (int d = 1; d < 16; d <<= 1) {
                int t = __shfl_up(y, d);
                if (lane >= d) y += t;
            }
            wsum[lane] = y;
        }
        __syncthreads();
        int waveoff = (w == 0) ? 0 : wsum[w - 1];
        if (i < N) offs[i] = s_carry + waveoff + x - v;
        __syncthreads();
        if (tid == 0) s_carry += wsum[15];
        __syncthreads();
    }
    if (tid == 0) offs[N] = s_carry;
}

__global__ __launch_bounds__(256) void csr_fill(
    const int* __restrict__ ei, const int* __restrict__ offs,
    int* __restrict__ cursor, int* __restrict__ csr_src,
    float* __restrict__ csr_nrm, const float* __restrict__ dinv, int E)
{
    for (int e = blockIdx.x * 256 + threadIdx.x; e < E; e += gridDim.x * 256) {
        int s = ei[e];
        int d = ei[NE + e];
        int pos = offs[d] + atomicAdd(&cursor[d], 1);
        csr_src[pos] = s;
        csr_nrm[pos] = dinv[s] * dinv[d];
    }
}

// ================= GCN gather (bf16 hw), one wave per dst node ================
template <int F, int ACT, int OUTBF>
__global__ __launch_bounds__(256) void gcn_gather(
    const int* __restrict__ offs, const int* __restrict__ csr_src,
    const float* __restrict__ csr_nrm, const ushortt* __restrict__ hw,
    const float* __restrict__ dinv, const float* __restrict__ bias,
    void* __restrict__ outb, int N)
{
    constexpr int VEC = F / 64;
    const int wid = blockIdx.x * 4 + (threadIdx.x >> 6);
    const int lane = threadIdx.x & 63;
    if (wid >= N) return;
    const int col = lane * VEC;

    float acc[VEC];
    float self = dinv[wid] * dinv[wid];
    if (VEC == 4) {
        ushort4 r = *(const ushort4*)(hw + (size_t)wid * F + col);
        acc[0] = self * b2f(r.x); acc[1] = self * b2f(r.y);
        acc[2] = self * b2f(r.z); acc[3] = self * b2f(r.w);
    } else {
        ushort2 r = *(const ushort2*)(hw + (size_t)wid * F + col);
        acc[0] = self * b2f(r.x); acc[1] = self * b2f(r.y);
    }

    int e = offs[wid];
    const int end = offs[wid + 1];
    for (; e + 1 < end; e += 2) {
        int s0 = csr_src[e], s1 = csr_src[e + 1];
        float n0 = csr_nrm[e], n1 = csr_nrm[e + 1];
        if (VEC == 4) {
            ushort4 r0 = *(const ushort4*)(hw + (size_t)s0 * F + col);
            ushort4 r1 = *(const ushort4*)(hw + (size_t)s1 * F + col);
            acc[0] = fmaf(n0, b2f(r0.x), acc[0]); acc[1] = fmaf(n0, b2f(r0.y), acc[1]);
            acc[2] = fmaf(n0, b2f(r0.z), acc[2]); acc[3] = fmaf(n0, b2f(r0.w), acc[3]);
            acc[0] = fmaf(n1, b2f(r1.x), acc[0]); acc[1] = fmaf(n1, b2f(r1.y), acc[1]);
            acc[2] = fmaf(n1, b2f(r1.z), acc[2]); acc[3] = fmaf(n1, b2f(r1.w), acc[3]);
        } else {
            ushort2 r0 = *(const ushort2*)(hw + (size_t)s0 * F + col);
            ushort2 r1 = *(const ushort2*)(hw + (size_t)s1 * F + col);
            acc[0] = fmaf(n0, b2f(r0.x), acc[0]); acc[1] = fmaf(n0, b2f(r0.y), acc[1]);
            acc[0] = fmaf(n1, b2f(r1.x), acc[0]); acc[1] = fmaf(n1, b2f(r1.y), acc[1]);
        }
    }
    if (e < end) {
        int s0 = csr_src[e];
        float n0 = csr_nrm[e];
        if (VEC == 4) {
            ushort4 r0 = *(const ushort4*)(hw + (size_t)s0 * F + col);
            acc[0] = fmaf(n0, b2f(r0.x), acc[0]); acc[1] = fmaf(n0, b2f(r0.y), acc[1]);
            acc[2] = fmaf(n0, b2f(r0.z), acc[2]); acc[3] = fmaf(n0, b2f(r0.w), acc[3]);
        } else {
            ushort2 r0 = *(const ushort2*)(hw + (size_t)s0 * F + col);
            acc[0] = fmaf(n0, b2f(r0.x), acc[0]); acc[1] = fmaf(n0, b2f(r0.y), acc[1]);
        }
    }

#pragma unroll
    for (int jj = 0; jj < VEC; ++jj) {
        acc[jj] += bias[col + jj];
        if (ACT == 1) acc[jj] = relu_f(acc[jj]);
    }
    if (OUTBF == 1) {
        ushortt* ob = (ushortt*)outb;
#pragma unroll
        for (int jj = 0; jj < VEC; ++jj)
            ob[(size_t)wid * F + col + jj] = bf16rn(acc[jj]);
    } else {
        float* ob = (float*)outb;
#pragma unroll
        for (int jj = 0; jj < VEC; ++jj)
            ob[(size_t)wid * F + col + jj] = acc[jj];
    }
}

// ================= launch ================
extern "C" void kernel_launch(void* const* d_in, const int* in_sizes, int n_in,
                              void* d_out, int out_size, void* d_ws, size_t ws_size,
                              hipStream_t stream)
{
    const float* x    = (const float*)d_in[0];
    const int*   ei   = (const int*)d_in[1];
    const float* w_go = (const float*)d_in[2];
    const float* b_go = (const float*)d_in[3];
    const float* w_re = (const float*)d_in[4];
    const float* b_re = (const float*)d_in[5];
    const float* w_me = (const float*)d_in[6];
    const float* b_me = (const float*)d_in[7];
    const float* w_gw = (const float*)d_in[8];
    const float* b_gw = (const float*)d_in[9];
    const float* ipw  = (const float*)d_in[10];
    const float* ipb  = (const float*)d_in[11];
    const float* opw  = (const float*)d_in[12];
    const float* opb  = (const float*)d_in[13];
    const float* w1   = (const float*)d_in[14];
    const float* b1   = (const float*)d_in[15];
    const float* w2   = (const float*)d_in[16];
    const float* b2   = (const float*)d_in[17];
    float* out = (float*)d_out;
    char* ws   = (char*)d_ws;

    size_t off = 0;
    auto alloc = [&](size_t bytes) { size_t o = off; off += (bytes + 255) & ~(size_t)255; return o; };
    const size_t o_dinv = alloc(NN * 4);
    const size_t o_deg  = alloc(NN * 4);
    const size_t o_offs = alloc((NN + 1) * 4);
    const size_t o_cur  = alloc(NN * 4);
    const size_t o_csrs = alloc((size_t)NE * 4);
    const size_t o_csrn = alloc((size_t)NE * 4);
    const size_t o_wgo  = alloc(256 * 512 * 2);
    const size_t o_wre  = alloc(256 * 256 * 2);
    const size_t o_wme  = alloc(256 * 256 * 2);
    const size_t o_ipw  = alloc(768 * 256 * 2);
    const size_t o_opw  = alloc(256 * 256 * 2);
    const size_t o_w1t  = alloc(256 * 256 * 2);
    const size_t o_w2t  = alloc(128 * 256 * 2);
    const size_t o_R1   = alloc((size_t)4 * NN * 768 * 2);  // qkv; ago/are/ame overlay
    const size_t o_R2   = alloc((size_t)4 * NN * 256 * 2);  // p, then o
    const size_t o_fus  = alloc((size_t)NN * 256 * 2);
    const size_t o_hw   = alloc((size_t)NN * 256 * 2);
    const size_t o_h1   = alloc((size_t)NN * 256 * 2);
    const size_t o_hw2  = alloc((size_t)NN * 128 * 2);

    float* f_dinv = (float*)(ws + o_dinv);
    int*   i_deg  = (int*)(ws + o_deg);
    int*   i_offs = (int*)(ws + o_offs);
    int*   i_cur  = (int*)(ws + o_cur);
    int*   i_csrs = (int*)(ws + o_csrs);
    float* f_csrn = (float*)(ws + o_csrn);
    ushortt* ago  = (ushortt*)(ws + o_R1);
    ushortt* are  = (ushortt*)(ws + o_R1 + (size_t)NN * 512 * 2);
    ushortt* ame  = (ushortt*)(ws + o_R1 + (size_t)NN * 768 * 2);
    ushortt* qkv  = (ushortt*)(ws + o_R1);
    ushortt* p    = (ushortt*)(ws + o_R2);
    ushortt* ob   = (ushortt*)(ws + o_R2);
    ushortt* fus  = (ushortt*)(ws + o_fus);
    ushortt* hw   = (ushortt*)(ws + o_hw);
    ushortt* h1   = (ushortt*)(ws + o_h1);
    ushortt* hw2  = (ushortt*)(ws + o_hw2);

    // ---- CSR build ----
    hipMemsetAsync(i_deg, 0, NN * 4, stream);
    hipMemsetAsync(i_cur, 0, NN * 4, stream);
    deg_int_kernel<<<1024, 256, 0, stream>>>(ei + NE, i_deg, NE);
    dinv_kernel<<<(NN + 255) / 256, 256, 0, stream>>>(i_deg, f_dinv, NN);
    scan_kernel<<<1, 1024, 0, stream>>>(i_deg, i_offs, NN);
    csr_fill<<<1024, 256, 0, stream>>>(ei, i_offs, i_cur, i_csrs, f_csrn, f_dinv, NE);

    // ---- weight conversions ----
    convT<<<(512 * 256 + 255) / 256, 256, 0, stream>>>(w_go, (ushortt*)(ws + o_wgo), 512, 256);
    convT<<<(256 * 256 + 255) / 256, 256, 0, stream>>>(w_re, (ushortt*)(ws + o_wre), 256, 256);
    convT<<<(256 * 256 + 255) / 256, 256, 0, stream>>>(w_me, (ushortt*)(ws + o_wme), 256, 256);
    convT<<<(256 * 256 + 255) / 256, 256, 0, stream>>>(w1,   (ushortt*)(ws + o_w1t), 256, 256);
    convT<<<(256 * 128 + 255) / 256, 256, 0, stream>>>(w2,   (ushortt*)(ws + o_w2t), 256, 128);
    convF<<<(768 * 256 + 255) / 256, 256, 0, stream>>>(ipw,  (ushortt*)(ws + o_ipw), 768 * 256);
    convF<<<(256 * 256 + 255) / 256, 256, 0, stream>>>(opw,  (ushortt*)(ws + o_opw), 256 * 256);

    // ---- x -> bf16 branch inputs ----
    conv_x<<<((long)NN * 128 + 255) / 256, 256, 0, stream>>>(x, ago, are, ame);

    // ---- branch projections: p rows n*4+t ----
    dim3 gGo(2, (NN + 127) / 128);
    gemm_mfma<1, 1><<<gGo, 256, 0, stream>>>(ago, 512, (ushortt*)(ws + o_wgo), p,           1024, b_go, NN, 512);
    gemm_mfma<1, 1><<<gGo, 256, 0, stream>>>(are, 256, (ushortt*)(ws + o_wre), p + 256,     1024, b_re, NN, 256);
    gemm_mfma<1, 1><<<gGo, 256, 0, stream>>>(ame, 256, (ushortt*)(ws + o_wme), p + 512,     1024, b_me, NN, 256);
    gw_kernel<<<((long)NN * 64 + 255) / 256, 256, 0, stream>>>(x, w_gw, b_gw, p);

    // ---- QKV projection ----
    dim3 gQ(6, (4 * NN + 127) / 128);
    gemm_mfma<0, 1><<<gQ, 256, 0, stream>>>(p, 256, (ushortt*)(ws + o_ipw), qkv, 768, ipb, 4 * NN, 256);

    // ---- attention (o overlays p) ----
    attn_kernel<<<(NN + 3) / 4, 256, 0, stream>>>(qkv, ob, NN);

    // ---- out_proj + fused mean (OUTMODE 2) ----
    dim3 gO(2, (4 * NN + 127) / 128);
    gemm_mfma<0, 2><<<gO, 256, 0, stream>>>(ob, 256, (ushortt*)(ws + o_opw), fus, 256, opb, 4 * NN, 256);

    // ---- GCN layer 1 ----
    dim3 gH(2, (NN + 127) / 128);
    gemm_mfma<0, 1><<<gH, 256, 0, stream>>>(fus, 256, (ushortt*)(ws + o_w1t), hw, 256, nullptr, NN, 256);
    gcn_gather<256, 1, 1><<<(NN + 3) / 4, 256, 0, stream>>>(i_offs, i_csrs, f_csrn, hw, f_dinv, b1, h1, NN);

    // ---- GCN layer 2 ----
    dim3 gH2(1, (NN + 127) / 128);
    gemm_mfma<0, 1><<<gH2, 256, 0, stream>>>(h1, 256, (ushortt*)(ws + o_w2t), hw2, 128, nullptr, NN, 256);
    gcn_gather<128, 0, 0><<<(NN + 3) / 4, 256, 0, stream>>>(i_offs, i_csrs, f_csrn, hw2, f_dinv, b2, out, NN);
}

// Round 4
// 1016.061 us; speedup vs baseline: 11.0243x; 1.0868x over previous
//
#include <hip/hip_runtime.h>
#include <cstdint>
#include <cstddef>

#define NN 50000
#define NE 1600000
#define XD 1025

typedef unsigned short ushortt;
typedef __attribute__((ext_vector_type(8))) short short8;
typedef __attribute__((ext_vector_type(4))) float f32x4;

__device__ __forceinline__ float relu_f(float v) { return v > 0.f ? v : 0.f; }
__device__ __forceinline__ float b2f(ushortt u) { return __uint_as_float(((unsigned)u) << 16); }
__device__ __forceinline__ float blo(unsigned u) { return __uint_as_float(u << 16); }
__device__ __forceinline__ float bhi(unsigned u) { return __uint_as_float(u & 0xffff0000u); }
__device__ __forceinline__ ushortt bf16rn(float f) {
    unsigned u = __float_as_uint(f);
    return (ushortt)((u + 0x7fffu + ((u >> 16) & 1u)) >> 16);
}
__device__ __forceinline__ void load_lds16(const void* g, void* l) {
    __builtin_amdgcn_global_load_lds(
        (const __attribute__((address_space(1))) void*)g,
        (__attribute__((address_space(3))) void*)l, 16, 0, 0);
}

// ================= bf16 MFMA GEMM (OUTMODE 1 only) =================
// A: (M,K) bf16 row-major, lda. Bt: (N,K) bf16 row-major. bias f32 or null.
template <int ACT>
__global__ __launch_bounds__(256) void gemm_mfma(
    const ushortt* __restrict__ A, int lda,
    const ushortt* __restrict__ Bt,
    ushortt* __restrict__ C, int ldc,
    const float* __restrict__ bias,
    int M, int K)
{
    __shared__ ushortt As[128 * 32];
    __shared__ ushortt Bs[128 * 32];
    const int tid = threadIdx.x;
    const int w = tid >> 6, l = tid & 63;
    const int wr = w >> 1, wc = w & 1;
    const int brow = blockIdx.y << 7;
    const int bcol = blockIdx.x << 7;

    f32x4 acc[4][4] = {};

    const int rA0 = wr * 64 + (l & 15);
    const int rB0 = wc * 64 + (l & 15);
    const int kslot = l >> 4;

    for (int k0 = 0; k0 < K; k0 += 32) {
#pragma unroll
        for (int c = 0; c < 2; ++c) {
            int rl = c * 64 + w * 16 + (l >> 2);
            int csel = (l & 3) ^ (rl & 3);
            int gr = brow + rl; if (gr >= M) gr = M - 1;
            load_lds16(A + (size_t)gr * lda + k0 + csel * 8, &As[(c * 64 + w * 16) * 32]);
        }
#pragma unroll
        for (int c = 0; c < 2; ++c) {
            int rl = c * 64 + w * 16 + (l >> 2);
            int csel = (l & 3) ^ (rl & 3);
            load_lds16(Bt + (size_t)(bcol + rl) * K + k0 + csel * 8, &Bs[(c * 64 + w * 16) * 32]);
        }
        __syncthreads();

        short8 af[4], bf[4];
#pragma unroll
        for (int mi = 0; mi < 4; ++mi) {
            int row = rA0 + mi * 16;
            af[mi] = *(const short8*)&As[row * 32 + ((kslot ^ (row & 3)) << 3)];
        }
#pragma unroll
        for (int ni = 0; ni < 4; ++ni) {
            int row = rB0 + ni * 16;
            bf[ni] = *(const short8*)&Bs[row * 32 + ((kslot ^ (row & 3)) << 3)];
        }
#pragma unroll
        for (int mi = 0; mi < 4; ++mi)
#pragma unroll
            for (int ni = 0; ni < 4; ++ni)
                acc[mi][ni] = __builtin_amdgcn_mfma_f32_16x16x32_bf16(af[mi], bf[ni], acc[mi][ni], 0, 0, 0);
        __syncthreads();
    }

    const int cb = bcol + wc * 64 + (l & 15);
    const int rb = brow + wr * 64 + ((l >> 4) << 2);
#pragma unroll
    for (int mi = 0; mi < 4; ++mi) {
#pragma unroll
        for (int ni = 0; ni < 4; ++ni) {
            int col = cb + ni * 16;
            float bv = bias ? bias[col] : 0.f;
#pragma unroll
            for (int r = 0; r < 4; ++r) {
                int row = rb + mi * 16 + r;
                if (row < M) {
                    float v = acc[mi][ni][r] + bv;
                    if (ACT == 1) v = relu_f(v);
                    C[(size_t)row * ldc + col] = bf16rn(v);
                }
            }
        }
    }
}

// ================= fused QKV + attention + token-mean =================
// p: (4*NN,256) bf16 rows n*4+t. ipw: (768,256) bf16. ipb: (768) f32.
// obar: (NN,256) bf16 = mean_t( softmax(qk^T/8) @ v )
// Block: 8 nodes = 32 rows, 4 waves. Wave w owns cols w*64..w*64+63 of each chunk.
__global__ __launch_bounds__(256) void fused_attn(
    const ushortt* __restrict__ p,
    const ushortt* __restrict__ ipw,
    const float* __restrict__ ipb,
    ushortt* __restrict__ obar)
{
    __shared__ __align__(16) ushortt p_s[32 * 256];   // 16B slots xor-swizzled by row&7
    __shared__ __align__(16) ushortt qs[32 * 264];    // +8 pad: bank spread
    __shared__ __align__(16) ushortt ks[32 * 264];
    __shared__ float attn_s[8][4][4][4];              // [node][h][ti][tj]
    __shared__ float asum_s[8][4][4];                 // [node][h][tj]

    const int tid = threadIdx.x;
    const int w = tid >> 6, l = tid & 63;
    const int nb = blockIdx.x << 3;
    const size_t r0 = (size_t)nb * 4;

    // ---- stage p: wave w stages rows w*8..w*8+7, swizzled source slots ----
    {
        const int slot = l & 31, rofs = l >> 5;
#pragma unroll
        for (int c = 0; c < 4; ++c) {
            int row = w * 8 + c * 2 + rofs;
            load_lds16(p + (r0 + row) * 256 + ((slot ^ (row & 7)) << 3),
                       &p_s[(w * 8 + c * 2) * 256]);
        }
    }
    __syncthreads();

    const int nq = w << 6;
    auto chunk = [&](int cc, ushortt* dst) {
        f32x4 acc[2][4] = {};
#pragma unroll
        for (int kk = 0; kk < 8; ++kk) {
            const int ar0 = l & 15, ar1 = ar0 + 16;
            const int slot = (kk << 2) + (l >> 4);
            short8 a0 = *(const short8*)&p_s[ar0 * 256 + ((slot ^ (ar0 & 7)) << 3)];
            short8 a1 = *(const short8*)&p_s[ar1 * 256 + ((slot ^ (ar1 & 7)) << 3)];
            short8 bv[4];
#pragma unroll
            for (int ni = 0; ni < 4; ++ni) {
                int brow = (cc << 8) + nq + (ni << 4) + (l & 15);
                bv[ni] = *(const short8*)&ipw[(size_t)brow * 256 + (kk << 5) + ((l >> 4) << 3)];
            }
#pragma unroll
            for (int ni = 0; ni < 4; ++ni) {
                acc[0][ni] = __builtin_amdgcn_mfma_f32_16x16x32_bf16(a0, bv[ni], acc[0][ni], 0, 0, 0);
                acc[1][ni] = __builtin_amdgcn_mfma_f32_16x16x32_bf16(a1, bv[ni], acc[1][ni], 0, 0, 0);
            }
        }
#pragma unroll
        for (int mt = 0; mt < 2; ++mt)
#pragma unroll
        for (int ni = 0; ni < 4; ++ni) {
            int col = nq + (ni << 4) + (l & 15);
            float bb = ipb[(cc << 8) + col];
#pragma unroll
            for (int r = 0; r < 4; ++r) {
                int row = (mt << 4) + ((l >> 4) << 2) + r;
                dst[row * 264 + col] = bf16rn(acc[mt][ni][r] + bb);
            }
        }
    };

    chunk(0, qs);   // q
    chunk(1, ks);   // k
    __syncthreads();

    // ---- scores + softmax: thread = (node,h,ti), 128 threads ----
    if (tid < 128) {
        const int node = tid >> 4, h = (tid >> 2) & 3, ti = tid & 3;
        const ushortt* qp = &qs[(node * 4 + ti) * 264 + (h << 6)];
        float s[4];
#pragma unroll
        for (int tj = 0; tj < 4; ++tj) {
            const ushortt* kp = &ks[(node * 4 + tj) * 264 + (h << 6)];
            float a = 0.f;
#pragma unroll
            for (int d8 = 0; d8 < 8; ++d8) {
                uint4 qa = *(const uint4*)(qp + d8 * 8);
                uint4 ka = *(const uint4*)(kp + d8 * 8);
                a += blo(qa.x) * blo(ka.x) + bhi(qa.x) * bhi(ka.x);
                a += blo(qa.y) * blo(ka.y) + bhi(qa.y) * bhi(ka.y);
                a += blo(qa.z) * blo(ka.z) + bhi(qa.z) * bhi(ka.z);
                a += blo(qa.w) * blo(ka.w) + bhi(qa.w) * bhi(ka.w);
            }
            s[tj] = a * 0.125f;
        }
        float m = fmaxf(fmaxf(s[0], s[1]), fmaxf(s[2], s[3]));
        float e0 = expf(s[0] - m), e1 = expf(s[1] - m), e2 = expf(s[2] - m), e3 = expf(s[3] - m);
        float inv = 1.f / (e0 + e1 + e2 + e3);
        attn_s[node][h][ti][0] = e0 * inv;
        attn_s[node][h][ti][1] = e1 * inv;
        attn_s[node][h][ti][2] = e2 * inv;
        attn_s[node][h][ti][3] = e3 * inv;
    }
    __syncthreads();

    // ---- token-mean of attn (mean commutes into PV) ----
    if (tid < 128) {
        const int node = tid >> 4, h = (tid >> 2) & 3, tj = tid & 3;
        asum_s[node][h][tj] = 0.25f * (attn_s[node][h][0][tj] + attn_s[node][h][1][tj] +
                                       attn_s[node][h][2][tj] + attn_s[node][h][3][tj]);
    }

    chunk(2, qs);   // v overwrites q (scores already consumed q)
    __syncthreads();

    // ---- obar[n,c] = sum_tj asum[n,h(c),tj] * v[n,tj,c] ----
    {
        const int node = tid >> 5;
        const int c8 = (tid & 31) << 3;
        const int h = c8 >> 6;
        const float a0 = asum_s[node][h][0], a1 = asum_s[node][h][1];
        const float a2 = asum_s[node][h][2], a3 = asum_s[node][h][3];
        uint4 u0 = *(const uint4*)&qs[(node * 4 + 0) * 264 + c8];
        uint4 u1 = *(const uint4*)&qs[(node * 4 + 1) * 264 + c8];
        uint4 u2 = *(const uint4*)&qs[(node * 4 + 2) * 264 + c8];
        uint4 u3 = *(const uint4*)&qs[(node * 4 + 3) * 264 + c8];
        float f0[8], f1[8], f2[8], f3[8];
        auto up = [](uint4 u, float* f) {
            f[0] = blo(u.x); f[1] = bhi(u.x); f[2] = blo(u.y); f[3] = bhi(u.y);
            f[4] = blo(u.z); f[5] = bhi(u.z); f[6] = blo(u.w); f[7] = bhi(u.w);
        };
        up(u0, f0); up(u1, f1); up(u2, f2); up(u3, f3);
        ushortt res[8];
#pragma unroll
        for (int i = 0; i < 8; ++i)
            res[i] = bf16rn(a0 * f0[i] + a1 * f1[i] + a2 * f2[i] + a3 * f3[i]);
        *(uint4*)&obar[(size_t)(nb + node) * 256 + c8] = *(uint4*)res;
    }
}

// ================= conversions =================
__global__ __launch_bounds__(256) void conv_x(
    const float* __restrict__ x, ushortt* __restrict__ ago,
    ushortt* __restrict__ are, ushortt* __restrict__ ame)
{
    long idx = blockIdx.x * 256L + threadIdx.x;
    if (idx >= (long)NN * 128) return;
    int n = (int)(idx >> 7);
    int c8 = ((int)idx & 127) << 3;
    const float* src = x + (size_t)n * XD + c8;
    ushortt* dst;
    if (c8 < 512) dst = ago + (size_t)n * 512 + c8;
    else if (c8 < 768) dst = are + (size_t)n * 256 + (c8 - 512);
    else dst = ame + (size_t)n * 256 + (c8 - 768);
    ushort4 o1, o2;
    o1.x = bf16rn(src[0]); o1.y = bf16rn(src[1]); o1.z = bf16rn(src[2]); o1.w = bf16rn(src[3]);
    o2.x = bf16rn(src[4]); o2.y = bf16rn(src[5]); o2.z = bf16rn(src[6]); o2.w = bf16rn(src[7]);
    *(ushort4*)dst = o1;
    *(ushort4*)(dst + 4) = o2;
}

__global__ __launch_bounds__(256) void convT(
    const float* __restrict__ in, ushortt* __restrict__ out, int R, int C)
{
    int idx = blockIdx.x * 256 + threadIdx.x;
    if (idx >= R * C) return;
    int c = idx / R, r = idx - c * R;
    out[idx] = bf16rn(in[(size_t)r * C + c]);
}

__global__ __launch_bounds__(256) void convF(
    const float* __restrict__ in, ushortt* __restrict__ out, int n)
{
    int idx = blockIdx.x * 256 + threadIdx.x;
    if (idx < n) out[idx] = bf16rn(in[idx]);
}

// ================= gw branch: p row n*4+3 ================
__global__ __launch_bounds__(256) void gw_kernel(
    const float* __restrict__ x, const float* __restrict__ w_gw,
    const float* __restrict__ b_gw, ushortt* __restrict__ p)
{
    long idx = blockIdx.x * 256L + threadIdx.x;
    if (idx >= (long)NN * 64) return;
    int n = (int)(idx >> 6);
    int c = ((int)idx & 63) << 2;
    float g = x[(size_t)n * XD + 1024];
    float4 w4 = *(const float4*)(w_gw + c);
    float4 b4 = *(const float4*)(b_gw + c);
    ushort4 r;
    r.x = bf16rn(relu_f(fmaf(g, w4.x, b4.x)));
    r.y = bf16rn(relu_f(fmaf(g, w4.y, b4.y)));
    r.z = bf16rn(relu_f(fmaf(g, w4.z, b4.z)));
    r.w = bf16rn(relu_f(fmaf(g, w4.w, b4.w)));
    *(ushort4*)(p + (size_t)n * 1024 + 768 + c) = r;
}

// ================= CSR build ================
__global__ __launch_bounds__(256) void deg_int_kernel(
    const int* __restrict__ dst, int* __restrict__ deg, int E)
{
    for (int e = blockIdx.x * 256 + threadIdx.x; e < E; e += gridDim.x * 256)
        atomicAdd(&deg[dst[e]], 1);
}

__global__ __launch_bounds__(256) void dinv_kernel(
    const int* __restrict__ deg, float* __restrict__ dinv, int N)
{
    int n = blockIdx.x * 256 + threadIdx.x;
    if (n < N) dinv[n] = rsqrtf((float)deg[n] + 1.0f);
}

__global__ __launch_bounds__(1024) void scan_kernel(
    const int* __restrict__ deg, int* __restrict__ offs, int N)
{
    __shared__ int wsum[16];
    __shared__ int s_carry;
    const int tid = threadIdx.x;
    const int lane = tid & 63;
    const int w = tid >> 6;
    if (tid == 0) s_carry = 0;
    __syncthreads();
    for (int base = 0; base < N; base += 1024) {
        int i = base + tid;
        int v = (i < N) ? deg[i] : 0;
        int x = v;
#pragma unroll
        for (int d = 1; d < 64; d <<= 1) {
            int t = __shfl_up(x, d);
            if (lane >= d) x += t;
        }
        if (lane == 63) wsum[w] = x;
        __syncthreads();
        if (w == 0 && lane < 16) {
            int y = wsum[lane];
#pragma unroll
            for (int d = 1; d < 16; d <<= 1) {
                int t = __shfl_up(y, d);
                if (lane >= d) y += t;
            }
            wsum[lane] = y;
        }
        __syncthreads();
        int waveoff = (w == 0) ? 0 : wsum[w - 1];
        if (i < N) offs[i] = s_carry + waveoff + x - v;
        __syncthreads();
        if (tid == 0) s_carry += wsum[15];
        __syncthreads();
    }
    if (tid == 0) offs[N] = s_carry;
}

__global__ __launch_bounds__(256) void csr_fill(
    const int* __restrict__ ei, const int* __restrict__ offs,
    int* __restrict__ cursor, int* __restrict__ csr_src,
    float* __restrict__ csr_nrm, const float* __restrict__ dinv, int E)
{
    for (int e = blockIdx.x * 256 + threadIdx.x; e < E; e += gridDim.x * 256) {
        int s = ei[e];
        int d = ei[NE + e];
        int pos = offs[d] + atomicAdd(&cursor[d], 1);
        csr_src[pos] = s;
        csr_nrm[pos] = dinv[s] * dinv[d];
    }
}

// ================= GCN gather ================
template <int F, int ACT, int OUTBF>
__global__ __launch_bounds__(256) void gcn_gather(
    const int* __restrict__ offs, const int* __restrict__ csr_src,
    const float* __restrict__ csr_nrm, const ushortt* __restrict__ hw,
    const float* __restrict__ dinv, const float* __restrict__ bias,
    void* __restrict__ outb, int N)
{
    constexpr int VEC = F / 64;
    const int wid = blockIdx.x * 4 + (threadIdx.x >> 6);
    const int lane = threadIdx.x & 63;
    if (wid >= N) return;
    const int col = lane * VEC;

    float acc[VEC];
    float self = dinv[wid] * dinv[wid];
    if (VEC == 4) {
        ushort4 r = *(const ushort4*)(hw + (size_t)wid * F + col);
        acc[0] = self * b2f(r.x); acc[1] = self * b2f(r.y);
        acc[2] = self * b2f(r.z); acc[3] = self * b2f(r.w);
    } else {
        ushort2 r = *(const ushort2*)(hw + (size_t)wid * F + col);
        acc[0] = self * b2f(r.x); acc[1] = self * b2f(r.y);
    }

    int e = offs[wid];
    const int end = offs[wid + 1];
    for (; e + 1 < end; e += 2) {
        int s0 = csr_src[e], s1 = csr_src[e + 1];
        float n0 = csr_nrm[e], n1 = csr_nrm[e + 1];
        if (VEC == 4) {
            ushort4 r0 = *(const ushort4*)(hw + (size_t)s0 * F + col);
            ushort4 r1 = *(const ushort4*)(hw + (size_t)s1 * F + col);
            acc[0] = fmaf(n0, b2f(r0.x), acc[0]); acc[1] = fmaf(n0, b2f(r0.y), acc[1]);
            acc[2] = fmaf(n0, b2f(r0.z), acc[2]); acc[3] = fmaf(n0, b2f(r0.w), acc[3]);
            acc[0] = fmaf(n1, b2f(r1.x), acc[0]); acc[1] = fmaf(n1, b2f(r1.y), acc[1]);
            acc[2] = fmaf(n1, b2f(r1.z), acc[2]); acc[3] = fmaf(n1, b2f(r1.w), acc[3]);
        } else {
            ushort2 r0 = *(const ushort2*)(hw + (size_t)s0 * F + col);
            ushort2 r1 = *(const ushort2*)(hw + (size_t)s1 * F + col);
            acc[0] = fmaf(n0, b2f(r0.x), acc[0]); acc[1] = fmaf(n0, b2f(r0.y), acc[1]);
            acc[0] = fmaf(n1, b2f(r1.x), acc[0]); acc[1] = fmaf(n1, b2f(r1.y), acc[1]);
        }
    }
    if (e < end) {
        int s0 = csr_src[e];
        float n0 = csr_nrm[e];
        if (VEC == 4) {
            ushort4 r0 = *(const ushort4*)(hw + (size_t)s0 * F + col);
            acc[0] = fmaf(n0, b2f(r0.x), acc[0]); acc[1] = fmaf(n0, b2f(r0.y), acc[1]);
            acc[2] = fmaf(n0, b2f(r0.z), acc[2]); acc[3] = fmaf(n0, b2f(r0.w), acc[3]);
        } else {
            ushort2 r0 = *(const ushort2*)(hw + (size_t)s0 * F + col);
            acc[0] = fmaf(n0, b2f(r0.x), acc[0]); acc[1] = fmaf(n0, b2f(r0.y), acc[1]);
        }
    }

#pragma unroll
    for (int jj = 0; jj < VEC; ++jj) {
        acc[jj] += bias[col + jj];
        if (ACT == 1) acc[jj] = relu_f(acc[jj]);
    }
    if (OUTBF == 1) {
        ushortt* ob = (ushortt*)outb;
#pragma unroll
        for (int jj = 0; jj < VEC; ++jj)
            ob[(size_t)wid * F + col + jj] = bf16rn(acc[jj]);
    } else {
        float* ob = (float*)outb;
#pragma unroll
        for (int jj = 0; jj < VEC; ++jj)
            ob[(size_t)wid * F + col + jj] = acc[jj];
    }
}

// ================= launch ================
extern "C" void kernel_launch(void* const* d_in, const int* in_sizes, int n_in,
                              void* d_out, int out_size, void* d_ws, size_t ws_size,
                              hipStream_t stream)
{
    const float* x    = (const float*)d_in[0];
    const int*   ei   = (const int*)d_in[1];
    const float* w_go = (const float*)d_in[2];
    const float* b_go = (const float*)d_in[3];
    const float* w_re = (const float*)d_in[4];
    const float* b_re = (const float*)d_in[5];
    const float* w_me = (const float*)d_in[6];
    const float* b_me = (const float*)d_in[7];
    const float* w_gw = (const float*)d_in[8];
    const float* b_gw = (const float*)d_in[9];
    const float* ipw  = (const float*)d_in[10];
    const float* ipb  = (const float*)d_in[11];
    const float* opw  = (const float*)d_in[12];
    const float* opb  = (const float*)d_in[13];
    const float* w1   = (const float*)d_in[14];
    const float* b1   = (const float*)d_in[15];
    const float* w2   = (const float*)d_in[16];
    const float* b2   = (const float*)d_in[17];
    float* out = (float*)d_out;
    char* ws   = (char*)d_ws;

    size_t off = 0;
    auto alloc = [&](size_t bytes) { size_t o = off; off += (bytes + 255) & ~(size_t)255; return o; };
    const size_t o_dinv = alloc(NN * 4);
    const size_t o_deg  = alloc(NN * 4);
    const size_t o_offs = alloc((NN + 1) * 4);
    const size_t o_cur  = alloc(NN * 4);
    const size_t o_csrs = alloc((size_t)NE * 4);
    const size_t o_csrn = alloc((size_t)NE * 4);
    const size_t o_wgo  = alloc(256 * 512 * 2);
    const size_t o_wre  = alloc(256 * 256 * 2);
    const size_t o_wme  = alloc(256 * 256 * 2);
    const size_t o_ipw  = alloc(768 * 256 * 2);
    const size_t o_opw  = alloc(256 * 256 * 2);
    const size_t o_w1t  = alloc(256 * 256 * 2);
    const size_t o_w2t  = alloc(128 * 256 * 2);
    const size_t o_pbr  = alloc((size_t)4 * NN * 256 * 2);  // p rows n*4+t
    const size_t o_x16  = alloc((size_t)NN * 1024 * 2);     // ago|are|ame
    const size_t o_obar = alloc((size_t)NN * 256 * 2);
    const size_t o_fus  = alloc((size_t)NN * 256 * 2);
    const size_t o_hw   = alloc((size_t)NN * 256 * 2);
    const size_t o_h1   = alloc((size_t)NN * 256 * 2);
    const size_t o_hw2  = alloc((size_t)NN * 128 * 2);

    float* f_dinv = (float*)(ws + o_dinv);
    int*   i_deg  = (int*)(ws + o_deg);
    int*   i_offs = (int*)(ws + o_offs);
    int*   i_cur  = (int*)(ws + o_cur);
    int*   i_csrs = (int*)(ws + o_csrs);
    float* f_csrn = (float*)(ws + o_csrn);
    ushortt* p    = (ushortt*)(ws + o_pbr);
    ushortt* ago  = (ushortt*)(ws + o_x16);
    ushortt* are  = ago + (size_t)NN * 512;
    ushortt* ame  = ago + (size_t)NN * 768;
    ushortt* ob   = (ushortt*)(ws + o_obar);
    ushortt* fus  = (ushortt*)(ws + o_fus);
    ushortt* hw   = (ushortt*)(ws + o_hw);
    ushortt* h1   = (ushortt*)(ws + o_h1);
    ushortt* hw2  = (ushortt*)(ws + o_hw2);

    // ---- CSR build ----
    hipMemsetAsync(i_deg, 0, NN * 4, stream);
    hipMemsetAsync(i_cur, 0, NN * 4, stream);
    deg_int_kernel<<<1024, 256, 0, stream>>>(ei + NE, i_deg, NE);
    dinv_kernel<<<(NN + 255) / 256, 256, 0, stream>>>(i_deg, f_dinv, NN);
    scan_kernel<<<1, 1024, 0, stream>>>(i_deg, i_offs, NN);
    csr_fill<<<1024, 256, 0, stream>>>(ei, i_offs, i_cur, i_csrs, f_csrn, f_dinv, NE);

    // ---- weight conversions ----
    convT<<<(512 * 256 + 255) / 256, 256, 0, stream>>>(w_go, (ushortt*)(ws + o_wgo), 512, 256);
    convT<<<(256 * 256 + 255) / 256, 256, 0, stream>>>(w_re, (ushortt*)(ws + o_wre), 256, 256);
    convT<<<(256 * 256 + 255) / 256, 256, 0, stream>>>(w_me, (ushortt*)(ws + o_wme), 256, 256);
    convT<<<(256 * 256 + 255) / 256, 256, 0, stream>>>(w1,   (ushortt*)(ws + o_w1t), 256, 256);
    convT<<<(256 * 128 + 255) / 256, 256, 0, stream>>>(w2,   (ushortt*)(ws + o_w2t), 256, 128);
    convF<<<(768 * 256 + 255) / 256, 256, 0, stream>>>(ipw,  (ushortt*)(ws + o_ipw), 768 * 256);
    convF<<<(256 * 256 + 255) / 256, 256, 0, stream>>>(opw,  (ushortt*)(ws + o_opw), 256 * 256);

    // ---- x -> bf16 branch inputs ----
    conv_x<<<((long)NN * 128 + 255) / 256, 256, 0, stream>>>(x, ago, are, ame);

    // ---- branch projections: p rows n*4+t (ldc=1024 interleave trick) ----
    dim3 gGo(2, (NN + 127) / 128);
    gemm_mfma<1><<<gGo, 256, 0, stream>>>(ago, 512, (ushortt*)(ws + o_wgo), p,       1024, b_go, NN, 512);
    gemm_mfma<1><<<gGo, 256, 0, stream>>>(are, 256, (ushortt*)(ws + o_wre), p + 256, 1024, b_re, NN, 256);
    gemm_mfma<1><<<gGo, 256, 0, stream>>>(ame, 256, (ushortt*)(ws + o_wme), p + 512, 1024, b_me, NN, 256);
    gw_kernel<<<((long)NN * 64 + 255) / 256, 256, 0, stream>>>(x, w_gw, b_gw, p);

    // ---- fused QKV + attention + token-mean ----
    fused_attn<<<NN / 8, 256, 0, stream>>>(p, (ushortt*)(ws + o_ipw), ipb, ob);

    // ---- out_proj on obar (mean commuted through): fus = obar @ opw^T + opb ----
    dim3 gOP(2, (NN + 127) / 128);
    gemm_mfma<0><<<gOP, 256, 0, stream>>>(ob, 256, (ushortt*)(ws + o_opw), fus, 256, opb, NN, 256);

    // ---- GCN layer 1 ----
    dim3 gH(2, (NN + 127) / 128);
    gemm_mfma<0><<<gH, 256, 0, stream>>>(fus, 256, (ushortt*)(ws + o_w1t), hw, 256, nullptr, NN, 256);
    gcn_gather<256, 1, 1><<<(NN + 3) / 4, 256, 0, stream>>>(i_offs, i_csrs, f_csrn, hw, f_dinv, b1, h1, NN);

    // ---- GCN layer 2 ----
    dim3 gH2(1, (NN + 127) / 128);
    gemm_mfma<0><<<gH2, 256, 0, stream>>>(h1, 256, (ushortt*)(ws + o_w2t), hw2, 128, nullptr, NN, 256);
    gcn_gather<128, 0, 0><<<(NN + 3) / 4, 256, 0, stream>>>(i_offs, i_csrs, f_csrn, hw2, f_dinv, b2, out, NN);
}